// Round 5
// baseline (417.672 us; speedup 1.0000x reference)
//
#include <hip/hip_runtime.h>
#include <hip/hip_bf16.h>

// out = blur(img[0]/max)*max == blur(img[0]) (linear blur; normalization cancels).
// Separable 25-tap Gaussian, sigma=4, replicate padding, C=3, H=W=4096, fp32.
//
// R5 change: XCD-bijective block remap (1D grid, 16512 = 8*2064 blocks).
// R4 A/B showed: dur 203->176us, but Occupancy stuck at 42% with LDS halved
// (occupancy is achieved, not resource-capped) and FETCH_SIZE = 1.47x ideal.
// Default x-fastest dispatch puts vertical neighbors (which share the 24-row
// halo = the big overlap) 43 blocks apart -> different XCDs -> halo re-reads
// miss L2, pay ~900cy HBM latency. Remap so each XCD walks column strips
// top-to-bottom: physical i -> L=(i&7)*2064+(i>>3); strip=L>>7 (one (c,x)
// pair), ty=L&127. Vertical halo then hits the same XCD's L2 (~200cy).
// Output is bit-identical (pure index remap).

#define IMG_W 4096
#define IMG_H 4096
#define N_CH  3
#define HALF  12
#define KSZ   25

#define TILE_W 96                 // output tile width
#define TILE_H 32                 // output tile height
#define COLS   (TILE_W + 2*HALF)  // 120 intermediate columns
#define LDS_STRIDE 124            // 16B-aligned rows; 124%32=28 spreads banks
#define GRP_ROWS 8                // output rows per vertical task
#define N_GRP    4                // 4 row groups -> 32 rows
#define VROWS (GRP_ROWS + 2*HALF) // 32 input rows per vertical task
#define VCOLS2 (COLS/2)           // 60 float2 columns
#define HCHUNK 12                 // output px per horizontal task (96/8)
#define HREAD  (HCHUNK + 2*HALF)  // 36 floats = 9 x b128

#define NBX   ((IMG_W + TILE_W - 1) / TILE_W)  // 43
#define NBY   (IMG_H / TILE_H)                 // 128
#define NWG   (NBX * NBY * N_CH)               // 16512 = 8 * 2064
#define WG_PER_XCD (NWG / 8)                   // 2064

// NOTE: no min-waves hint in __launch_bounds__. A previous (256,5) hint
// forced VGPR=48 and spilled ~40 floats/thread to scratch (1.6x slower).

__device__ __constant__ float kW[KSZ] = {
    0.00110988f, 0.00227883f, 0.00438965f, 0.00794860f, 0.01352109f,
    0.02160664f, 0.03243540f, 0.04574124f, 0.06059730f, 0.07541456f,
    0.08816855f, 0.09683420f, 0.09990806f, 0.09683420f, 0.08816855f,
    0.07541456f, 0.06059730f, 0.04574124f, 0.03243540f, 0.02160664f,
    0.01352109f, 0.00794860f, 0.00438965f, 0.00227883f, 0.00110988f
};

__global__ __launch_bounds__(256)
void gauss_blur_fused(const float* __restrict__ img, float* __restrict__ out)
{
    __shared__ float inter[TILE_H * LDS_STRIDE]; // 32*124*4 = 15872 B

    const int tid = threadIdx.x;

    // XCD-bijective remap: WG i presumed dispatched to XCD i%8 (round-robin).
    // Logical id L walks y fastest within a (c,x) strip; XCD k owns
    // L in [k*2064,(k+1)*2064) -> ~16 consecutive strips walked vertically.
    const int i  = blockIdx.x;
    const int L  = ((i & 7) * WG_PER_XCD) + (i >> 3);
    const int ty = L & (NBY - 1);          // 0..127
    const int strip = L >> 7;              // 0..128 (43*3 = 129 strips)
    const int c  = strip / NBX;            // 0..2
    const int bx = strip - c * NBX;        // 0..42

    const int x0 = bx * TILE_W;
    const int y0 = ty * TILE_H;

    const float* __restrict__ src = img + (size_t)c * IMG_W * IMG_H;
    float* __restrict__ dst       = out + (size_t)c * IMG_W * IMG_H;

    // ---------------- vertical pass: float2 columns, streaming accumulators.
    // Input row j (0..31) contributes kW[j-i] to outputs i in [j-24, j] n [0,7].
    // Per output the adds still arrive k=0..24 ascending (bit-identical order).
    if (tid < VCOLS2 * N_GRP) {          // 240 active
        const int c2 = tid % VCOLS2;     // 0..59
        const int g  = tid / VCOLS2;     // 0..3
        const int gx = x0 - HALF + 2 * c2;       // even; pairs never straddle an edge
        const int ybase = y0 + g * GRP_ROWS - HALF;
        const int ldscol = 2 * c2;

        float2 acc[GRP_ROWS];            // 8 float2 accumulators (16 VGPR)
        #pragma unroll
        for (int ii = 0; ii < GRP_ROWS; ++ii) { acc[ii].x = 0.f; acc[ii].y = 0.f; }

        if (gx >= 0 && gx <= IMG_W - 2) {
            if (ybase >= 0 && ybase + VROWS <= IMG_H) {
                // interior fast path
                const float* p = src + (size_t)ybase * IMG_W + gx;
                #pragma unroll
                for (int j = 0; j < VROWS; ++j) {
                    const float2 wv = *(const float2*)(p + (size_t)j * IMG_W);
                    const int ilo = (j - (KSZ - 1)) < 0 ? 0 : (j - (KSZ - 1));
                    const int ihi = j < (GRP_ROWS - 1) ? j : (GRP_ROWS - 1);
                    #pragma unroll
                    for (int ii = ilo; ii <= ihi; ++ii) {
                        const float kk = kW[j - ii];
                        acc[ii].x += kk * wv.x;
                        acc[ii].y += kk * wv.y;
                    }
                }
            } else {
                // y-edge: clamp rows
                #pragma unroll
                for (int j = 0; j < VROWS; ++j) {
                    int gy = ybase + j;
                    gy = gy < 0 ? 0 : (gy > IMG_H - 1 ? IMG_H - 1 : gy);
                    const float2 wv = *(const float2*)(src + (size_t)gy * IMG_W + gx);
                    const int ilo = (j - (KSZ - 1)) < 0 ? 0 : (j - (KSZ - 1));
                    const int ihi = j < (GRP_ROWS - 1) ? j : (GRP_ROWS - 1);
                    #pragma unroll
                    for (int ii = ilo; ii <= ihi; ++ii) {
                        const float kk = kW[j - ii];
                        acc[ii].x += kk * wv.x;
                        acc[ii].y += kk * wv.y;
                    }
                }
            }
        } else {
            // x-edge: whole pair clamps to the same edge column (gx always even)
            const int gc = gx < 0 ? 0 : IMG_W - 1;
            #pragma unroll
            for (int j = 0; j < VROWS; ++j) {
                int gy = ybase + j;
                gy = gy < 0 ? 0 : (gy > IMG_H - 1 ? IMG_H - 1 : gy);
                const float v = src[(size_t)gy * IMG_W + gc];
                const int ilo = (j - (KSZ - 1)) < 0 ? 0 : (j - (KSZ - 1));
                const int ihi = j < (GRP_ROWS - 1) ? j : (GRP_ROWS - 1);
                #pragma unroll
                for (int ii = ilo; ii <= ihi; ++ii) {
                    const float kk = kW[j - ii];
                    acc[ii].x += kk * v;
                    acc[ii].y += kk * v;
                }
            }
        }

        #pragma unroll
        for (int ii = 0; ii < GRP_ROWS; ++ii)
            *(float2*)&inter[(g * GRP_ROWS + ii) * LDS_STRIDE + ldscol] = acc[ii];
    }
    __syncthreads();

    // ---------------- horizontal pass: b128 LDS reads, streaming accumulators
    // 32 rows x 8 chunks x 12 px = 256 threads, all active.
    {
        const int row   = tid >> 3;        // 0..31
        const int chunk = tid & 7;         // 0..7
        const int xl    = chunk * HCHUNK;  // 0,12,..,84 -> 48B steps, 16B aligned

        float acc[HCHUNK];                 // 12 accumulators
        #pragma unroll
        for (int j = 0; j < HCHUNK; ++j) acc[j] = 0.f;

        const float4* lp = (const float4*)&inter[row * LDS_STRIDE + xl];
        #pragma unroll
        for (int m4 = 0; m4 < HREAD / 4; ++m4) {   // 9 x ds_read_b128
            const float4 t = lp[m4];
            #pragma unroll
            for (int e = 0; e < 4; ++e) {
                const int m = 4 * m4 + e;
                const float wv = (e == 0) ? t.x : (e == 1) ? t.y : (e == 2) ? t.z : t.w;
                const int jlo = (m - (KSZ - 1)) < 0 ? 0 : (m - (KSZ - 1));
                const int jhi = m < (HCHUNK - 1) ? m : (HCHUNK - 1);
                #pragma unroll
                for (int j = jlo; j <= jhi; ++j)
                    acc[j] += kW[m - j] * wv;
            }
        }

        const size_t rowbase = (size_t)(y0 + row) * IMG_W;
        const int gx0 = x0 + xl;
        #pragma unroll
        for (int j4 = 0; j4 < HCHUNK / 4; ++j4) {
            float4 o;
            o.x = acc[4 * j4 + 0]; o.y = acc[4 * j4 + 1];
            o.z = acc[4 * j4 + 2]; o.w = acc[4 * j4 + 3];
            const int gx = gx0 + 4 * j4;            // multiple of 4
            if (gx < IMG_W)
                *(float4*)&dst[rowbase + gx] = o;
        }
    }
}

extern "C" void kernel_launch(void* const* d_in, const int* in_sizes, int n_in,
                              void* d_out, int out_size, void* d_ws, size_t ws_size,
                              hipStream_t stream)
{
    const float* img = (const float*)d_in[0];
    float* out = (float*)d_out;

    dim3 grid(NWG);   // 16512, 1D; kernel decodes (c, bx, ty) via XCD remap
    dim3 block(256);
    gauss_blur_fused<<<grid, block, 0, stream>>>(img, out);
}

// Round 6
// 398.694 us; speedup vs baseline: 1.0476x; 1.0476x over previous
//
#include <hip/hip_runtime.h>
#include <hip/hip_bf16.h>

// out = blur(img[0]/max)*max == blur(img[0]) (linear blur; normalization cancels).
// Separable 25-tap Gaussian, sigma=4, replicate padding, C=3, H=W=4096, fp32.
//
// R6 change: force packed v_pk_fma_f32 via ext_vector_type math.
//  - R5 A/B: XCD remap made FETCH ideal (288->196 GB.KB) but dur WORSE
//    (176->188us) => fetch/halo latency NOT binding; remap reverted here.
//  - Every round: VALUBusy ~30%, HBM ~35%, Occupancy pinned 42% regardless
//    of LDS size => time ~ VALU instr count / 0.30. So: halve instr count.
//  - Vertical pass: f2 (2xf32) accumulators -> 200 packed FMA/thread.
//  - Horizontal pass: adjacent output columns paired into f2 accs using a
//    zero-padded pair table kW2[d]=(kW[d],kW[d-1]) -> 156 packed FMA/thread
//    (was 300 scalar). Tap order per output unchanged (ascending), fused
//    per-lane semantics identical => bit-identical output (absmax 0.00390625).

#define IMG_W 4096
#define IMG_H 4096
#define N_CH  3
#define HALF  12
#define KSZ   25

#define TILE_W 96                 // output tile width
#define TILE_H 32                 // output tile height
#define COLS   (TILE_W + 2*HALF)  // 120 intermediate columns
#define LDS_STRIDE 124            // 16B-aligned rows; 124%32=28 spreads banks
#define GRP_ROWS 8                // output rows per vertical task
#define N_GRP    4                // 4 row groups -> 32 rows
#define VROWS (GRP_ROWS + 2*HALF) // 32 input rows per vertical task
#define VCOLS2 (COLS/2)           // 60 float2 columns
#define HCHUNK 12                 // output px per horizontal task (96/8)
#define HPAIRS (HCHUNK/2)         // 6 f2 accumulators
#define HREAD  (HCHUNK + 2*HALF)  // 36 floats = 9 x b128

typedef float f2 __attribute__((ext_vector_type(2)));
typedef float f4 __attribute__((ext_vector_type(4)));

// NOTE: no min-waves hint in __launch_bounds__. A previous (256,5) hint
// forced VGPR=48 and spilled ~40 floats/thread to scratch (1.6x slower).

__device__ __constant__ float kW[KSZ] = {
    0.00110988f, 0.00227883f, 0.00438965f, 0.00794860f, 0.01352109f,
    0.02160664f, 0.03243540f, 0.04574124f, 0.06059730f, 0.07541456f,
    0.08816855f, 0.09683420f, 0.09990806f, 0.09683420f, 0.08816855f,
    0.07541456f, 0.06059730f, 0.04574124f, 0.03243540f, 0.02160664f,
    0.01352109f, 0.00794860f, 0.00438965f, 0.00227883f, 0.00110988f
};

// kW2[d] = (kW[d], kW[d-1]) zero-padded at d=0 (y lane) and d=25 (x lane).
// acc2[p] = (col 2p, col 2p+1); contribution of input column m uses d = m-2p.
__device__ __constant__ f2 kW2[26] = {
    {0.00110988f, 0.f},
    {0.00227883f, 0.00110988f},
    {0.00438965f, 0.00227883f},
    {0.00794860f, 0.00438965f},
    {0.01352109f, 0.00794860f},
    {0.02160664f, 0.01352109f},
    {0.03243540f, 0.02160664f},
    {0.04574124f, 0.03243540f},
    {0.06059730f, 0.04574124f},
    {0.07541456f, 0.06059730f},
    {0.08816855f, 0.07541456f},
    {0.09683420f, 0.08816855f},
    {0.09990806f, 0.09683420f},
    {0.09683420f, 0.09990806f},
    {0.08816855f, 0.09683420f},
    {0.07541456f, 0.08816855f},
    {0.06059730f, 0.07541456f},
    {0.04574124f, 0.06059730f},
    {0.03243540f, 0.04574124f},
    {0.02160664f, 0.03243540f},
    {0.01352109f, 0.02160664f},
    {0.00794860f, 0.01352109f},
    {0.00438965f, 0.00794860f},
    {0.00227883f, 0.00438965f},
    {0.00110988f, 0.00227883f},
    {0.f,         0.00110988f}
};

__global__ __launch_bounds__(256)
void gauss_blur_fused(const float* __restrict__ img, float* __restrict__ out)
{
    __shared__ float inter[TILE_H * LDS_STRIDE]; // 32*124*4 = 15872 B

    const int tid = threadIdx.x;
    const int x0  = blockIdx.x * TILE_W;
    const int y0  = blockIdx.y * TILE_H;
    const int c   = blockIdx.z;

    const float* __restrict__ src = img + (size_t)c * IMG_W * IMG_H;
    float* __restrict__ dst       = out + (size_t)c * IMG_W * IMG_H;

    // ---------------- vertical pass: f2 columns, streaming packed accumulators.
    // Input row j (0..31) contributes kW[j-i] to outputs i in [j-24, j] n [0,7].
    // Per output the adds arrive k=0..24 ascending (bit-identical order).
    if (tid < VCOLS2 * N_GRP) {          // 240 active
        const int c2 = tid % VCOLS2;     // 0..59
        const int g  = tid / VCOLS2;     // 0..3
        const int gx = x0 - HALF + 2 * c2;       // even; pairs never straddle an edge
        const int ybase = y0 + g * GRP_ROWS - HALF;
        const int ldscol = 2 * c2;

        f2 acc[GRP_ROWS];                // 8 packed accumulators (16 VGPR)
        #pragma unroll
        for (int ii = 0; ii < GRP_ROWS; ++ii) acc[ii] = (f2)(0.f);

        if (gx >= 0 && gx <= IMG_W - 2) {
            if (ybase >= 0 && ybase + VROWS <= IMG_H) {
                // interior fast path
                const float* p = src + (size_t)ybase * IMG_W + gx;
                #pragma unroll
                for (int j = 0; j < VROWS; ++j) {
                    const f2 wv = *(const f2*)(p + (size_t)j * IMG_W);
                    const int ilo = (j - (KSZ - 1)) < 0 ? 0 : (j - (KSZ - 1));
                    const int ihi = j < (GRP_ROWS - 1) ? j : (GRP_ROWS - 1);
                    #pragma unroll
                    for (int ii = ilo; ii <= ihi; ++ii)
                        acc[ii] += kW[j - ii] * wv;    // v_pk_fma_f32
                }
            } else {
                // y-edge: clamp rows
                #pragma unroll
                for (int j = 0; j < VROWS; ++j) {
                    int gy = ybase + j;
                    gy = gy < 0 ? 0 : (gy > IMG_H - 1 ? IMG_H - 1 : gy);
                    const f2 wv = *(const f2*)(src + (size_t)gy * IMG_W + gx);
                    const int ilo = (j - (KSZ - 1)) < 0 ? 0 : (j - (KSZ - 1));
                    const int ihi = j < (GRP_ROWS - 1) ? j : (GRP_ROWS - 1);
                    #pragma unroll
                    for (int ii = ilo; ii <= ihi; ++ii)
                        acc[ii] += kW[j - ii] * wv;
                }
            }
        } else {
            // x-edge: whole pair clamps to the same edge column (gx always even)
            const int gc = gx < 0 ? 0 : IMG_W - 1;
            #pragma unroll
            for (int j = 0; j < VROWS; ++j) {
                int gy = ybase + j;
                gy = gy < 0 ? 0 : (gy > IMG_H - 1 ? IMG_H - 1 : gy);
                const float v = src[(size_t)gy * IMG_W + gc];
                const f2 wv = {v, v};
                const int ilo = (j - (KSZ - 1)) < 0 ? 0 : (j - (KSZ - 1));
                const int ihi = j < (GRP_ROWS - 1) ? j : (GRP_ROWS - 1);
                #pragma unroll
                for (int ii = ilo; ii <= ihi; ++ii)
                    acc[ii] += kW[j - ii] * wv;
            }
        }

        #pragma unroll
        for (int ii = 0; ii < GRP_ROWS; ++ii)
            *(f2*)&inter[(g * GRP_ROWS + ii) * LDS_STRIDE + ldscol] = acc[ii];
    }
    __syncthreads();

    // ---------------- horizontal pass: b128 LDS reads, paired packed accumulators
    // 32 rows x 8 chunks x 12 px = 256 threads, all active.
    {
        const int row   = tid >> 3;        // 0..31
        const int chunk = tid & 7;         // 0..7
        const int xl    = chunk * HCHUNK;  // 0,12,..,84 -> 48B steps, 16B aligned

        f2 acc2[HPAIRS];                   // 6 packed accumulators (12 VGPR)
        #pragma unroll
        for (int p = 0; p < HPAIRS; ++p) acc2[p] = (f2)(0.f);

        const f4* lp = (const f4*)&inter[row * LDS_STRIDE + xl];
        #pragma unroll
        for (int m4 = 0; m4 < HREAD / 4; ++m4) {   // 9 x ds_read_b128
            const f4 t = lp[m4];
            #pragma unroll
            for (int e = 0; e < 4; ++e) {
                const int m = 4 * m4 + e;
                const float wv = t[e];
                // pairs p with tap index d = m-2p in [0,25]
                const int pmin = (m >= 25) ? (m - 24) / 2 : 0;   // ceil((m-25)/2)
                const int pmax = (m / 2) < (HPAIRS - 1) ? (m / 2) : (HPAIRS - 1);
                #pragma unroll
                for (int p = pmin; p <= pmax; ++p)
                    acc2[p] += wv * kW2[m - 2 * p];   // v_pk_fma_f32
            }
        }

        const size_t rowbase = (size_t)(y0 + row) * IMG_W;
        const int gx0 = x0 + xl;
        #pragma unroll
        for (int j4 = 0; j4 < HCHUNK / 4; ++j4) {
            f4 o;
            o.x = acc2[2 * j4 + 0].x; o.y = acc2[2 * j4 + 0].y;
            o.z = acc2[2 * j4 + 1].x; o.w = acc2[2 * j4 + 1].y;
            const int gx = gx0 + 4 * j4;            // multiple of 4
            if (gx < IMG_W)
                *(f4*)&dst[rowbase + gx] = o;
        }
    }
}

extern "C" void kernel_launch(void* const* d_in, const int* in_sizes, int n_in,
                              void* d_out, int out_size, void* d_ws, size_t ws_size,
                              hipStream_t stream)
{
    const float* img = (const float*)d_in[0];
    float* out = (float*)d_out;

    dim3 grid((IMG_W + TILE_W - 1) / TILE_W,  // 43
              IMG_H / TILE_H,                 // 128
              N_CH);                          // 3
    dim3 block(256);
    gauss_blur_fused<<<grid, block, 0, stream>>>(img, out);
}

// Round 7
// 387.483 us; speedup vs baseline: 1.0779x; 1.0289x over previous
//
#include <hip/hip_runtime.h>
#include <hip/hip_bf16.h>

// out = blur(img[0]/max)*max == blur(img[0]) (linear blur; normalization cancels).
// Separable 25-tap Gaussian, sigma=4, replicate padding, C=3, H=W=4096, fp32.
//
// R7 change: prefetch-ALL-loads-then-compute in both passes (deep per-wave MLP).
// Evidence chain: dur ~177us invariant to VALU count (R6 pk-fma flat, VGPR
// 52->44), fetch bytes (R5 -32% fetch = slower), occupancy (R6 42->54% flat),
// LDS size (R4). Per-block lifetime ~11us vs ~1.2us of VALU issue => waves
// are ~90% stalled on memory. VGPR=44 shows the allocator batches only ~2-4
// loads in flight per wave (s_waitcnt every ~25 FMAs, ~200-900cy exposed).
// Fix: vertical loads all 32 f2 rows into w[32] (64 VGPR) BEFORE the
// accumulate loop -> compiler emits progressive vmcnt(31..0) drain, 16KB in
// flight per wave (8x deeper). Horizontal likewise preloads all 9 f4 LDS
// reads. Same packed ops, same ascending-k order per output => bit-identical
// (absmax 0.00390625).

#define IMG_W 4096
#define IMG_H 4096
#define N_CH  3
#define HALF  12
#define KSZ   25

#define TILE_W 96                 // output tile width
#define TILE_H 32                 // output tile height
#define COLS   (TILE_W + 2*HALF)  // 120 intermediate columns
#define LDS_STRIDE 124            // 16B-aligned rows; 124%32=28 spreads banks
#define GRP_ROWS 8                // output rows per vertical task
#define N_GRP    4                // 4 row groups -> 32 rows
#define VROWS (GRP_ROWS + 2*HALF) // 32 input rows per vertical task
#define VCOLS2 (COLS/2)           // 60 float2 columns
#define HCHUNK 12                 // output px per horizontal task (96/8)
#define HPAIRS (HCHUNK/2)         // 6 f2 accumulators
#define HREAD  (HCHUNK + 2*HALF)  // 36 floats = 9 x b128

typedef float f2 __attribute__((ext_vector_type(2)));
typedef float f4 __attribute__((ext_vector_type(4)));

__device__ __constant__ float kW[KSZ] = {
    0.00110988f, 0.00227883f, 0.00438965f, 0.00794860f, 0.01352109f,
    0.02160664f, 0.03243540f, 0.04574124f, 0.06059730f, 0.07541456f,
    0.08816855f, 0.09683420f, 0.09990806f, 0.09683420f, 0.08816855f,
    0.07541456f, 0.06059730f, 0.04574124f, 0.03243540f, 0.02160664f,
    0.01352109f, 0.00794860f, 0.00438965f, 0.00227883f, 0.00110988f
};

// kW2[d] = (kW[d], kW[d-1]) zero-padded at d=0 (y lane) and d=25 (x lane).
// acc2[p] = (col 2p, col 2p+1); contribution of input column m uses d = m-2p.
__device__ __constant__ f2 kW2[26] = {
    {0.00110988f, 0.f},
    {0.00227883f, 0.00110988f},
    {0.00438965f, 0.00227883f},
    {0.00794860f, 0.00438965f},
    {0.01352109f, 0.00794860f},
    {0.02160664f, 0.01352109f},
    {0.03243540f, 0.02160664f},
    {0.04574124f, 0.03243540f},
    {0.06059730f, 0.04574124f},
    {0.07541456f, 0.06059730f},
    {0.08816855f, 0.07541456f},
    {0.09683420f, 0.08816855f},
    {0.09990806f, 0.09683420f},
    {0.09683420f, 0.09990806f},
    {0.08816855f, 0.09683420f},
    {0.07541456f, 0.08816855f},
    {0.06059730f, 0.07541456f},
    {0.04574124f, 0.06059730f},
    {0.03243540f, 0.04574124f},
    {0.02160664f, 0.03243540f},
    {0.01352109f, 0.02160664f},
    {0.00794860f, 0.01352109f},
    {0.00438965f, 0.00794860f},
    {0.00227883f, 0.00438965f},
    {0.00110988f, 0.00227883f},
    {0.f,         0.00110988f}
};

__global__ __launch_bounds__(256)
void gauss_blur_fused(const float* __restrict__ img, float* __restrict__ out)
{
    __shared__ float inter[TILE_H * LDS_STRIDE]; // 32*124*4 = 15872 B

    const int tid = threadIdx.x;
    const int x0  = blockIdx.x * TILE_W;
    const int y0  = blockIdx.y * TILE_H;
    const int c   = blockIdx.z;

    const float* __restrict__ src = img + (size_t)c * IMG_W * IMG_H;
    float* __restrict__ dst       = out + (size_t)c * IMG_W * IMG_H;

    // ---------------- vertical pass: prefetch all 32 f2 rows, then convolve.
    if (tid < VCOLS2 * N_GRP) {          // 240 active
        const int c2 = tid % VCOLS2;     // 0..59
        const int g  = tid / VCOLS2;     // 0..3
        const int gx = x0 - HALF + 2 * c2;       // even; pairs never straddle an edge
        const int ybase = y0 + g * GRP_ROWS - HALF;
        const int ldscol = 2 * c2;

        f2 w[VROWS];                     // 32 f2 = 64 VGPR, all loads in flight

        if (gx >= 0 && gx <= IMG_W - 2) {
            if (ybase >= 0 && ybase + VROWS <= IMG_H) {
                // interior fast path: 32 independent loads issued back-to-back
                const float* p = src + (size_t)ybase * IMG_W + gx;
                #pragma unroll
                for (int j = 0; j < VROWS; ++j)
                    w[j] = *(const f2*)(p + (size_t)j * IMG_W);
            } else {
                // y-edge: clamp rows (addresses all computable upfront)
                #pragma unroll
                for (int j = 0; j < VROWS; ++j) {
                    int gy = ybase + j;
                    gy = gy < 0 ? 0 : (gy > IMG_H - 1 ? IMG_H - 1 : gy);
                    w[j] = *(const f2*)(src + (size_t)gy * IMG_W + gx);
                }
            }
        } else {
            // x-edge: whole pair clamps to the same edge column (gx always even)
            const int gc = gx < 0 ? 0 : IMG_W - 1;
            #pragma unroll
            for (int j = 0; j < VROWS; ++j) {
                int gy = ybase + j;
                gy = gy < 0 ? 0 : (gy > IMG_H - 1 ? IMG_H - 1 : gy);
                const float v = src[(size_t)gy * IMG_W + gc];
                w[j].x = v; w[j].y = v;
            }
        }

        // gather form, ascending k per output: bit-identical order to R6
        #pragma unroll
        for (int i = 0; i < GRP_ROWS; ++i) {
            f2 a = (f2)(0.f);
            #pragma unroll
            for (int k = 0; k < KSZ; ++k)
                a += kW[k] * w[i + k];   // v_pk_fma_f32, static index
            *(f2*)&inter[(g * GRP_ROWS + i) * LDS_STRIDE + ldscol] = a;
        }
    }
    __syncthreads();

    // ---------------- horizontal pass: preload all 9 b128 reads, then convolve.
    // 32 rows x 8 chunks x 12 px = 256 threads, all active.
    {
        const int row   = tid >> 3;        // 0..31
        const int chunk = tid & 7;         // 0..7
        const int xl    = chunk * HCHUNK;  // 0,12,..,84 -> 48B steps, 16B aligned

        f4 t[HREAD / 4];                   // 9 f4 = 36 VGPR, all ds_reads in flight
        const f4* lp = (const f4*)&inter[row * LDS_STRIDE + xl];
        #pragma unroll
        for (int m4 = 0; m4 < HREAD / 4; ++m4)
            t[m4] = lp[m4];

        f2 acc2[HPAIRS];                   // 6 packed accumulators
        #pragma unroll
        for (int p = 0; p < HPAIRS; ++p) acc2[p] = (f2)(0.f);

        #pragma unroll
        for (int m4 = 0; m4 < HREAD / 4; ++m4) {
            #pragma unroll
            for (int e = 0; e < 4; ++e) {
                const int m = 4 * m4 + e;
                const float wv = t[m4][e];
                // pairs p with tap index d = m-2p in [0,25]
                const int pmin = (m >= 25) ? (m - 24) / 2 : 0;
                const int pmax = (m / 2) < (HPAIRS - 1) ? (m / 2) : (HPAIRS - 1);
                #pragma unroll
                for (int p = pmin; p <= pmax; ++p)
                    acc2[p] += wv * kW2[m - 2 * p];   // v_pk_fma_f32
            }
        }

        const size_t rowbase = (size_t)(y0 + row) * IMG_W;
        const int gx0 = x0 + xl;
        #pragma unroll
        for (int j4 = 0; j4 < HCHUNK / 4; ++j4) {
            f4 o;
            o.x = acc2[2 * j4 + 0].x; o.y = acc2[2 * j4 + 0].y;
            o.z = acc2[2 * j4 + 1].x; o.w = acc2[2 * j4 + 1].y;
            const int gx = gx0 + 4 * j4;            // multiple of 4
            if (gx < IMG_W)
                *(f4*)&dst[rowbase + gx] = o;
        }
    }
}

extern "C" void kernel_launch(void* const* d_in, const int* in_sizes, int n_in,
                              void* d_out, int out_size, void* d_ws, size_t ws_size,
                              hipStream_t stream)
{
    const float* img = (const float*)d_in[0];
    float* out = (float*)d_out;

    dim3 grid((IMG_W + TILE_W - 1) / TILE_W,  // 43
              IMG_H / TILE_H,                 // 128
              N_CH);                          // 3
    dim3 block(256);
    gauss_blur_fused<<<grid, block, 0, stream>>>(img, out);
}

// Round 8
// 344.157 us; speedup vs baseline: 1.2136x; 1.1259x over previous
//
#include <hip/hip_runtime.h>
#include <hip/hip_bf16.h>

// out = blur(img[0]/max)*max == blur(img[0]) (linear blur; normalization cancels).
// Separable 25-tap Gaussian, sigma=4, replicate padding, C=3, H=W=4096, fp32.
//
// R8 change: async fire-and-forget staging of the input tile into LDS via
// __builtin_amdgcn_global_load_lds (16B), for interior blocks (94%).
// Evidence chain: R7's prefetch-all was defeated by the register allocator
// (VGPR stayed 44 -> loads re-sunk, MLP still shallow, dur only 177->168).
// global_load_lds has no VGPR destination -> allocator CANNOT serialize it;
// all ~27KB of tile loads stay in flight per wave, one vmcnt(0)+barrier.
// Vertical pass then reads LDS (latency ~120cy, easily hidden) instead of
// global (~200-900cy exposed). Edge blocks keep the R7 global path (replicate
// clamping breaks DMA contiguity). Same values, same add order per output =>
// bit-identical (absmax 0.00390625).
//
// DMA layout proof: flat in_lds index f = row*120+col, col 4-aligned quads
// never cross a row (120%4==0); global addr src+(y0-12+row)*4096+(x0-12)+col
// is 16B-aligned since x0-12 = 96*bx-12 == 0 (mod 4). LDS dest per chunk is
// wave-uniform &in_lds[chunk*256], HW writes lane*16 -> exactly flat order.

#define IMG_W 4096
#define IMG_H 4096
#define N_CH  3
#define HALF  12
#define KSZ   25

#define TILE_W 96                 // output tile width
#define TILE_H 32                 // output tile height
#define COLS   (TILE_W + 2*HALF)  // 120 intermediate columns
#define LDS_STRIDE 124            // 16B-aligned rows; 124%32=28 spreads banks
#define GRP_ROWS 8                // output rows per vertical task
#define N_GRP    4                // 4 row groups -> 32 rows
#define VROWS (GRP_ROWS + 2*HALF) // 32 input rows per vertical task
#define VCOLS2 (COLS/2)           // 60 float2 columns
#define HCHUNK 12                 // output px per horizontal task (96/8)
#define HPAIRS (HCHUNK/2)         // 6 f2 accumulators
#define HREAD  (HCHUNK + 2*HALF)  // 36 floats = 9 x b128

#define IN_ROWS   (TILE_H + 2*HALF)    // 56 staged input rows
#define IN_FLAT   (IN_ROWS * COLS)     // 6720 valid floats
#define IN_CHUNKS 27                   // ceil(6720/256)
#define IN_PAD    (IN_CHUNKS * 256)    // 6912 floats = 27648 B

typedef float f2 __attribute__((ext_vector_type(2)));
typedef float f4 __attribute__((ext_vector_type(4)));

typedef const __attribute__((address_space(1))) void gas_t;
typedef __attribute__((address_space(3))) void las_t;

__device__ __constant__ float kW[KSZ] = {
    0.00110988f, 0.00227883f, 0.00438965f, 0.00794860f, 0.01352109f,
    0.02160664f, 0.03243540f, 0.04574124f, 0.06059730f, 0.07541456f,
    0.08816855f, 0.09683420f, 0.09990806f, 0.09683420f, 0.08816855f,
    0.07541456f, 0.06059730f, 0.04574124f, 0.03243540f, 0.02160664f,
    0.01352109f, 0.00794860f, 0.00438965f, 0.00227883f, 0.00110988f
};

// kW2[d] = (kW[d], kW[d-1]) zero-padded at d=0 (y lane) and d=25 (x lane).
// acc2[p] = (col 2p, col 2p+1); contribution of input column m uses d = m-2p.
__device__ __constant__ f2 kW2[26] = {
    {0.00110988f, 0.f},
    {0.00227883f, 0.00110988f},
    {0.00438965f, 0.00227883f},
    {0.00794860f, 0.00438965f},
    {0.01352109f, 0.00794860f},
    {0.02160664f, 0.01352109f},
    {0.03243540f, 0.02160664f},
    {0.04574124f, 0.03243540f},
    {0.06059730f, 0.04574124f},
    {0.07541456f, 0.06059730f},
    {0.08816855f, 0.07541456f},
    {0.09683420f, 0.08816855f},
    {0.09990806f, 0.09683420f},
    {0.09683420f, 0.09990806f},
    {0.08816855f, 0.09683420f},
    {0.07541456f, 0.08816855f},
    {0.06059730f, 0.07541456f},
    {0.04574124f, 0.06059730f},
    {0.03243540f, 0.04574124f},
    {0.02160664f, 0.03243540f},
    {0.01352109f, 0.02160664f},
    {0.00794860f, 0.01352109f},
    {0.00438965f, 0.00794860f},
    {0.00227883f, 0.00438965f},
    {0.00110988f, 0.00227883f},
    {0.f,         0.00110988f}
};

__global__ __launch_bounds__(256)
void gauss_blur_fused(const float* __restrict__ img, float* __restrict__ out)
{
    __shared__ float in_lds[IN_PAD];             // 27648 B staged input tile
    __shared__ float inter[TILE_H * LDS_STRIDE]; // 15872 B intermediate

    const int tid = threadIdx.x;
    const int bx  = blockIdx.x;
    const int ty  = blockIdx.y;
    const int x0  = bx * TILE_W;
    const int y0  = ty * TILE_H;
    const int c   = blockIdx.z;

    const float* __restrict__ src = img + (size_t)c * IMG_W * IMG_H;
    float* __restrict__ dst       = out + (size_t)c * IMG_W * IMG_H;

    const bool interior = (bx >= 1) && (bx <= 41) && (ty >= 1) && (ty <= 126);

    if (interior) {
        // ---------- async DMA staging: 27 chunks x 1KB, fire-and-forget
        const int w    = tid >> 6;   // wave 0..3 (uniform per wave)
        const int lane = tid & 63;
        const float* gbase = src + (size_t)(y0 - HALF) * IMG_W + (x0 - HALF);
        #pragma unroll
        for (int k = 0; k < 7; ++k) {
            const int chunk = 4 * k + w;
            if (chunk < IN_CHUNKS) {
                int fo = chunk * 256 + lane * 4;
                fo = fo > (IN_FLAT - 4) ? (IN_FLAT - 4) : fo;  // pad lanes clamp
                const int r   = fo / COLS;
                const int col = fo - r * COLS;
                __builtin_amdgcn_global_load_lds(
                    (gas_t*)(gbase + (size_t)r * IMG_W + col),
                    (las_t*)&in_lds[chunk * 256],
                    16, 0, 0);
            }
        }
        __syncthreads();   // vmcnt(0) drain + barrier: tile ready in LDS

        // ---------- vertical pass from LDS
        if (tid < VCOLS2 * N_GRP) {          // 240 active
            const int c2 = tid % VCOLS2;     // 0..59
            const int g  = tid / VCOLS2;     // 0..3
            const int ldscol = 2 * c2;
            const float* ip = &in_lds[g * GRP_ROWS * COLS + 2 * c2];

            f2 wrow[VROWS];
            #pragma unroll
            for (int j = 0; j < VROWS; ++j)
                wrow[j] = *(const f2*)(ip + j * COLS);

            #pragma unroll
            for (int i = 0; i < GRP_ROWS; ++i) {
                f2 a = (f2)(0.f);
                #pragma unroll
                for (int k = 0; k < KSZ; ++k)
                    a += kW[k] * wrow[i + k];   // v_pk_fma_f32, ascending k
                *(f2*)&inter[(g * GRP_ROWS + i) * LDS_STRIDE + ldscol] = a;
            }
        }
    } else {
        // ---------- edge blocks: R7 vertical pass from global with clamps
        if (tid < VCOLS2 * N_GRP) {
            const int c2 = tid % VCOLS2;
            const int g  = tid / VCOLS2;
            const int gx = x0 - HALF + 2 * c2;   // even; pairs never straddle an edge
            const int ybase = y0 + g * GRP_ROWS - HALF;
            const int ldscol = 2 * c2;

            f2 wrow[VROWS];

            if (gx >= 0 && gx <= IMG_W - 2) {
                if (ybase >= 0 && ybase + VROWS <= IMG_H) {
                    const float* p = src + (size_t)ybase * IMG_W + gx;
                    #pragma unroll
                    for (int j = 0; j < VROWS; ++j)
                        wrow[j] = *(const f2*)(p + (size_t)j * IMG_W);
                } else {
                    #pragma unroll
                    for (int j = 0; j < VROWS; ++j) {
                        int gy = ybase + j;
                        gy = gy < 0 ? 0 : (gy > IMG_H - 1 ? IMG_H - 1 : gy);
                        wrow[j] = *(const f2*)(src + (size_t)gy * IMG_W + gx);
                    }
                }
            } else {
                const int gc = gx < 0 ? 0 : IMG_W - 1;
                #pragma unroll
                for (int j = 0; j < VROWS; ++j) {
                    int gy = ybase + j;
                    gy = gy < 0 ? 0 : (gy > IMG_H - 1 ? IMG_H - 1 : gy);
                    const float v = src[(size_t)gy * IMG_W + gc];
                    wrow[j].x = v; wrow[j].y = v;
                }
            }

            #pragma unroll
            for (int i = 0; i < GRP_ROWS; ++i) {
                f2 a = (f2)(0.f);
                #pragma unroll
                for (int k = 0; k < KSZ; ++k)
                    a += kW[k] * wrow[i + k];
                *(f2*)&inter[(g * GRP_ROWS + i) * LDS_STRIDE + ldscol] = a;
            }
        }
    }
    __syncthreads();

    // ---------------- horizontal pass: preload 9 b128 LDS reads, then convolve.
    // 32 rows x 8 chunks x 12 px = 256 threads, all active.
    {
        const int row   = tid >> 3;        // 0..31
        const int chunk = tid & 7;         // 0..7
        const int xl    = chunk * HCHUNK;  // 0,12,..,84 -> 48B steps, 16B aligned

        f4 t[HREAD / 4];                   // 9 f4
        const f4* lp = (const f4*)&inter[row * LDS_STRIDE + xl];
        #pragma unroll
        for (int m4 = 0; m4 < HREAD / 4; ++m4)
            t[m4] = lp[m4];

        f2 acc2[HPAIRS];                   // 6 packed accumulators
        #pragma unroll
        for (int p = 0; p < HPAIRS; ++p) acc2[p] = (f2)(0.f);

        #pragma unroll
        for (int m4 = 0; m4 < HREAD / 4; ++m4) {
            #pragma unroll
            for (int e = 0; e < 4; ++e) {
                const int m = 4 * m4 + e;
                const float wv = t[m4][e];
                // pairs p with tap index d = m-2p in [0,25]
                const int pmin = (m >= 25) ? (m - 24) / 2 : 0;
                const int pmax = (m / 2) < (HPAIRS - 1) ? (m / 2) : (HPAIRS - 1);
                #pragma unroll
                for (int p = pmin; p <= pmax; ++p)
                    acc2[p] += wv * kW2[m - 2 * p];   // v_pk_fma_f32
            }
        }

        const size_t rowbase = (size_t)(y0 + row) * IMG_W;
        const int gx0 = x0 + xl;
        #pragma unroll
        for (int j4 = 0; j4 < HCHUNK / 4; ++j4) {
            f4 o;
            o.x = acc2[2 * j4 + 0].x; o.y = acc2[2 * j4 + 0].y;
            o.z = acc2[2 * j4 + 1].x; o.w = acc2[2 * j4 + 1].y;
            const int gx = gx0 + 4 * j4;            // multiple of 4
            if (gx < IMG_W)
                *(f4*)&dst[rowbase + gx] = o;
        }
    }
}

extern "C" void kernel_launch(void* const* d_in, const int* in_sizes, int n_in,
                              void* d_out, int out_size, void* d_ws, size_t ws_size,
                              hipStream_t stream)
{
    const float* img = (const float*)d_in[0];
    float* out = (float*)d_out;

    dim3 grid((IMG_W + TILE_W - 1) / TILE_W,  // 43
              IMG_H / TILE_H,                 // 128
              N_CH);                          // 3
    dim3 block(256);
    gauss_blur_fused<<<grid, block, 0, stream>>>(img, out);
}